// Round 1
// baseline (5129.456 us; speedup 1.0000x reference)
//
#include <hip/hip_runtime.h>
#include <hip/hip_bf16.h>
#include <math.h>

// TinyTransformerLM fp32 baseline for MI355X.
// Sizes fixed per reference: V=32000 D=512 L=4 H=8 DFF=2048 S=1024 B=4 DK=64.
#define TT_V   32000
#define TT_D   512
#define TT_L   4
#define TT_H   8
#define TT_DFF 2048
#define TT_S   1024
#define TT_B   4
#define TT_DK  64
#define TT_M   (TT_B * TT_S)   /* 4096 token rows */
#define TT_EPS 1e-5f

// ---------------------------------------------------------------- embed
// x[row, :] = tok_emb[idx[row], :] + pos_emb[row % S, :]
__global__ __launch_bounds__(128) void k_embed(const int* __restrict__ idx,
                                               const float* __restrict__ tok,
                                               const float* __restrict__ pos,
                                               float* __restrict__ x) {
    const int row = blockIdx.x;            // b*S + s
    const int s   = row & (TT_S - 1);
    const int t   = idx[row];
    const float4* tp = (const float4*)(tok + (size_t)t * TT_D);
    const float4* pp = (const float4*)(pos + (size_t)s * TT_D);
    float4* xp = (float4*)(x + (size_t)row * TT_D);
    const int i = threadIdx.x;             // D/4 = 128 exactly
    float4 a = tp[i], b = pp[i];
    xp[i] = make_float4(a.x + b.x, a.y + b.y, a.z + b.z, a.w + b.w);
}

// ---------------------------------------------------------------- layernorm
// One wave (64 lanes) per row; 4 rows per 256-thread block. float4 loads,
// pure shfl reductions (no LDS, no barriers).
__global__ __launch_bounds__(256) void k_layernorm(const float* __restrict__ in,
                                                   const float* __restrict__ w,
                                                   const float* __restrict__ b,
                                                   float* __restrict__ out) {
    const int row  = blockIdx.x * 4 + (threadIdx.x >> 6);
    const int lane = threadIdx.x & 63;
    const float4* xr = (const float4*)(in + (size_t)row * TT_D);
    float4 v0 = xr[lane];
    float4 v1 = xr[lane + 64];
    float sum = v0.x + v0.y + v0.z + v0.w + v1.x + v1.y + v1.z + v1.w;
#pragma unroll
    for (int off = 32; off >= 1; off >>= 1) sum += __shfl_xor(sum, off, 64);
    const float mu = sum * (1.0f / TT_D);
    float ss = 0.f, dx;
    dx = v0.x - mu; ss += dx * dx;
    dx = v0.y - mu; ss += dx * dx;
    dx = v0.z - mu; ss += dx * dx;
    dx = v0.w - mu; ss += dx * dx;
    dx = v1.x - mu; ss += dx * dx;
    dx = v1.y - mu; ss += dx * dx;
    dx = v1.z - mu; ss += dx * dx;
    dx = v1.w - mu; ss += dx * dx;
#pragma unroll
    for (int off = 32; off >= 1; off >>= 1) ss += __shfl_xor(ss, off, 64);
    const float rs = rsqrtf(ss * (1.0f / TT_D) + TT_EPS);
    const float4* wp = (const float4*)w;
    const float4* bp = (const float4*)b;
    float4 w0 = wp[lane], w1 = wp[lane + 64];
    float4 b0 = bp[lane], b1 = bp[lane + 64];
    float4* op = (float4*)(out + (size_t)row * TT_D);
    op[lane] = make_float4((v0.x - mu) * rs * w0.x + b0.x,
                           (v0.y - mu) * rs * w0.y + b0.y,
                           (v0.z - mu) * rs * w0.z + b0.z,
                           (v0.w - mu) * rs * w0.w + b0.w);
    op[lane + 64] = make_float4((v1.x - mu) * rs * w1.x + b1.x,
                                (v1.y - mu) * rs * w1.y + b1.y,
                                (v1.z - mu) * rs * w1.z + b1.z,
                                (v1.w - mu) * rs * w1.w + b1.w);
}

// ---------------------------------------------------------------- GEMM (NT)
// C[M,N] = A[M,K] @ B[N,K]^T (+bias[N]) (+resid[M,N]) (ReLU optional).
// Both A and B are K-contiguous (torch Linear W is [out,in]) -> coalesced
// float4 global loads along K. BM=128 BN=64 BK=16, 256 threads, 8x4/thread.
// All problem dims divide tile dims (32000 = 500*64), so no bounds checks.
template <int RELU, int RESID, int BIAS>
__global__ __launch_bounds__(256) void k_gemm_nt(const float* __restrict__ A,
                                                 const float* __restrict__ Bm,
                                                 const float* __restrict__ bias,
                                                 const float* __restrict__ resid,
                                                 float* __restrict__ C,
                                                 int M, int N, int K) {
    constexpr int BM = 128, BN = 64, BK = 16;
    __shared__ float As[BK][BM + 4];   // +4 pad: store conflicts 2-way (free)
    __shared__ float Bs[BK][BN + 4];
    const int m0  = blockIdx.y * BM;
    const int n0  = blockIdx.x * BN;
    const int tid = threadIdx.x;
    const int tm  = tid >> 4;  // 0..15 -> 8 output rows each
    const int tn  = tid & 15;  // 0..15 -> 4 output cols each
    const int br  = tid >> 2;  // B-tile load row
    const int bkq = tid & 3;   // B-tile load k-quad

    float acc[8][4];
#pragma unroll
    for (int i = 0; i < 8; ++i)
#pragma unroll
        for (int j = 0; j < 4; ++j) acc[i][j] = 0.f;

    for (int k0 = 0; k0 < K; k0 += BK) {
#pragma unroll
        for (int u = 0; u < 2; ++u) {        // A tile: 512 float4, 2/thread
            const int f  = tid * 2 + u;
            const int r  = f >> 2;
            const int kq = f & 3;
            float4 a = *(const float4*)(A + (size_t)(m0 + r) * K + k0 + kq * 4);
            As[kq * 4 + 0][r] = a.x;
            As[kq * 4 + 1][r] = a.y;
            As[kq * 4 + 2][r] = a.z;
            As[kq * 4 + 3][r] = a.w;
        }
        {                                     // B tile: 256 float4, 1/thread
            float4 bv = *(const float4*)(Bm + (size_t)(n0 + br) * K + k0 + bkq * 4);
            Bs[bkq * 4 + 0][br] = bv.x;
            Bs[bkq * 4 + 1][br] = bv.y;
            Bs[bkq * 4 + 2][br] = bv.z;
            Bs[bkq * 4 + 3][br] = bv.w;
        }
        __syncthreads();
#pragma unroll
        for (int k = 0; k < BK; ++k) {
            float a[8], bb[4];
            *(float4*)(a)     = *(const float4*)&As[k][tm * 8];
            *(float4*)(a + 4) = *(const float4*)&As[k][tm * 8 + 4];
            *(float4*)(bb)    = *(const float4*)&Bs[k][tn * 4];
#pragma unroll
            for (int i = 0; i < 8; ++i)
#pragma unroll
                for (int j = 0; j < 4; ++j)
                    acc[i][j] = fmaf(a[i], bb[j], acc[i][j]);
        }
        __syncthreads();
    }

    float4 bv = make_float4(0.f, 0.f, 0.f, 0.f);
    if (BIAS) bv = *(const float4*)(bias + n0 + tn * 4);
#pragma unroll
    for (int i = 0; i < 8; ++i) {
        const int m = m0 + tm * 8 + i;
        float4 c = make_float4(acc[i][0] + bv.x, acc[i][1] + bv.y,
                               acc[i][2] + bv.z, acc[i][3] + bv.w);
        if (RESID) {   // same thread reads+writes the same address: no race
            float4 rv = *(const float4*)(resid + (size_t)m * N + n0 + tn * 4);
            c.x += rv.x; c.y += rv.y; c.z += rv.z; c.w += rv.w;
        }
        if (RELU) {
            c.x = fmaxf(c.x, 0.f); c.y = fmaxf(c.y, 0.f);
            c.z = fmaxf(c.z, 0.f); c.w = fmaxf(c.w, 0.f);
        }
        *(float4*)(C + (size_t)m * N + n0 + tn * 4) = c;
    }
}

// ---------------------------------------------------------------- attention
// Flash-style causal attention, fp32. Block = (b, h, 64-row q-tile),
// 256 threads; thread (tr,tc) owns a 4x4 patch. Row groups = 16 contiguous
// lanes -> width-16 shfl reductions for online softmax.
// Layout: q/k/v/o are [B,S,D] with head h occupying cols h*64..h*64+63.
__global__ __launch_bounds__(256) void k_attn(const float* __restrict__ Qm,
                                              const float* __restrict__ Km,
                                              const float* __restrict__ Vm,
                                              float* __restrict__ Om) {
    __shared__ float Qs[64][68];
    __shared__ float Ks[64][68];
    __shared__ float Vs[64][68];
    __shared__ float Ps[64][68];
    const int qt = blockIdx.x;     // q tile 0..15
    const int hh = blockIdx.y;
    const int bb = blockIdx.z;
    const size_t base = (size_t)bb * TT_S * TT_D + (size_t)hh * TT_DK;
    const int tid = threadIdx.x;
    const int tr = tid >> 4, tc = tid & 15;

    for (int i = tid; i < 64 * 16; i += 256) {
        const int r = i >> 4, cq = i & 15;
        *(float4*)&Qs[r][cq * 4] =
            *(const float4*)(Qm + base + (size_t)(qt * 64 + r) * TT_D + cq * 4);
    }
    float m_run[4], l_run[4], acc[4][4];
#pragma unroll
    for (int i = 0; i < 4; ++i) {
        m_run[i] = -INFINITY;
        l_run[i] = 0.f;
#pragma unroll
        for (int j = 0; j < 4; ++j) acc[i][j] = 0.f;
    }
    __syncthreads();

    for (int kt = 0; kt <= qt; ++kt) {
        for (int i = tid; i < 64 * 16; i += 256) {
            const int r = i >> 4, cq = i & 15;
            *(float4*)&Ks[r][cq * 4] =
                *(const float4*)(Km + base + (size_t)(kt * 64 + r) * TT_D + cq * 4);
            *(float4*)&Vs[r][cq * 4] =
                *(const float4*)(Vm + base + (size_t)(kt * 64 + r) * TT_D + cq * 4);
        }
        __syncthreads();

        // scores: S = Q K^T * 1/sqrt(64)
        float s[4][4];
#pragma unroll
        for (int i = 0; i < 4; ++i)
#pragma unroll
            for (int j = 0; j < 4; ++j) s[i][j] = 0.f;
#pragma unroll
        for (int d4 = 0; d4 < 16; ++d4) {
            float4 qv[4], kv[4];
#pragma unroll
            for (int i = 0; i < 4; ++i) qv[i] = *(const float4*)&Qs[tr * 4 + i][d4 * 4];
#pragma unroll
            for (int j = 0; j < 4; ++j) kv[j] = *(const float4*)&Ks[tc * 4 + j][d4 * 4];
#pragma unroll
            for (int i = 0; i < 4; ++i)
#pragma unroll
                for (int j = 0; j < 4; ++j)
                    s[i][j] += qv[i].x * kv[j].x + qv[i].y * kv[j].y +
                               qv[i].z * kv[j].z + qv[i].w * kv[j].w;
        }
#pragma unroll
        for (int i = 0; i < 4; ++i)
#pragma unroll
            for (int j = 0; j < 4; ++j) s[i][j] *= 0.125f;
        if (kt == qt) {  // causal mask on the diagonal tile
#pragma unroll
            for (int i = 0; i < 4; ++i)
#pragma unroll
                for (int j = 0; j < 4; ++j)
                    if (tc * 4 + j > tr * 4 + i) s[i][j] = -INFINITY;
        }

        // online softmax per owned row
#pragma unroll
        for (int i = 0; i < 4; ++i) {
            float mx = fmaxf(fmaxf(s[i][0], s[i][1]), fmaxf(s[i][2], s[i][3]));
#pragma unroll
            for (int off = 8; off >= 1; off >>= 1) mx = fmaxf(mx, __shfl_xor(mx, off, 16));
            const float m_new = fmaxf(m_run[i], mx);
            const float sc = expf(m_run[i] - m_new);   // 0 when m_run = -inf
            float rsum = 0.f;
#pragma unroll
            for (int j = 0; j < 4; ++j) {
                const float p = expf(s[i][j] - m_new);
                Ps[tr * 4 + i][tc * 4 + j] = p;
                rsum += p;
            }
#pragma unroll
            for (int off = 8; off >= 1; off >>= 1) rsum += __shfl_xor(rsum, off, 16);
            l_run[i] = l_run[i] * sc + rsum;
            m_run[i] = m_new;
#pragma unroll
            for (int j = 0; j < 4; ++j) acc[i][j] *= sc;
        }
        __syncthreads();   // Ps visible to all

        // O += P V  (thread owns rows tr*4..+3, head-dims tc*4..+3)
        for (int c = 0; c < 64; ++c) {
            const float4 vv = *(const float4*)&Vs[c][tc * 4];
#pragma unroll
            for (int i = 0; i < 4; ++i) {
                const float p = Ps[tr * 4 + i][c];
                acc[i][0] = fmaf(p, vv.x, acc[i][0]);
                acc[i][1] = fmaf(p, vv.y, acc[i][1]);
                acc[i][2] = fmaf(p, vv.z, acc[i][2]);
                acc[i][3] = fmaf(p, vv.w, acc[i][3]);
            }
        }
        __syncthreads();   // before K/V/P overwrite next iteration
    }

#pragma unroll
    for (int i = 0; i < 4; ++i) {
        const float inv = 1.f / l_run[i];
        *(float4*)(Om + base + (size_t)(qt * 64 + tr * 4 + i) * TT_D + tc * 4) =
            make_float4(acc[i][0] * inv, acc[i][1] * inv,
                        acc[i][2] * inv, acc[i][3] * inv);
    }
}

// ---------------------------------------------------------------- launch
extern "C" void kernel_launch(void* const* d_in, const int* in_sizes, int n_in,
                              void* d_out, int out_size, void* d_ws, size_t ws_size,
                              hipStream_t stream) {
    const int*   idx  = (const int*)  d_in[0];
    const float* tok  = (const float*)d_in[1];
    const float* pos  = (const float*)d_in[2];
    const float* Wq   = (const float*)d_in[3];
    const float* bq   = (const float*)d_in[4];
    const float* Wk   = (const float*)d_in[5];
    const float* bk   = (const float*)d_in[6];
    const float* Wv   = (const float*)d_in[7];
    const float* bv   = (const float*)d_in[8];
    const float* Wo   = (const float*)d_in[9];
    const float* bo   = (const float*)d_in[10];
    const float* ln1w = (const float*)d_in[11];
    const float* ln1b = (const float*)d_in[12];
    const float* ln2w = (const float*)d_in[13];
    const float* ln2b = (const float*)d_in[14];
    const float* W1   = (const float*)d_in[15];
    const float* b1   = (const float*)d_in[16];
    const float* W2   = (const float*)d_in[17];
    const float* b2   = (const float*)d_in[18];
    const float* lnfw = (const float*)d_in[19];
    const float* lnfb = (const float*)d_in[20];
    float* out = (float*)d_out;

    // workspace layout (fp32): x,h,q,k,v,o = 8 MB each; mid = 32 MB; total 80 MB
    const size_t NROW = (size_t)TT_M * TT_D;
    float* x   = (float*)d_ws;
    float* h   = x  + NROW;
    float* q   = h  + NROW;
    float* kb  = q  + NROW;
    float* vb  = kb + NROW;
    float* o   = vb + NROW;
    float* mid = o  + NROW;      // TT_M * TT_DFF

    const dim3 gDD(TT_D / 64, TT_M / 128);    // (8, 32)   D->D GEMMs
    const dim3 gF1(TT_DFF / 64, TT_M / 128);  // (32, 32)  FFN up
    const dim3 gHd(TT_V / 64, TT_M / 128);    // (500, 32) LM head

    k_embed<<<TT_M, 128, 0, stream>>>(idx, tok, pos, x);

    for (int l = 0; l < TT_L; ++l) {
        const float* Wq_l = Wq + (size_t)l * TT_D * TT_D;
        const float* Wk_l = Wk + (size_t)l * TT_D * TT_D;
        const float* Wv_l = Wv + (size_t)l * TT_D * TT_D;
        const float* Wo_l = Wo + (size_t)l * TT_D * TT_D;
        const float* W1_l = W1 + (size_t)l * TT_DFF * TT_D;
        const float* W2_l = W2 + (size_t)l * TT_D * TT_DFF;

        k_layernorm<<<TT_M / 4, 256, 0, stream>>>(x, ln1w + l * TT_D, ln1b + l * TT_D, h);
        k_gemm_nt<0, 0, 1><<<gDD, 256, 0, stream>>>(h, Wq_l, bq + l * TT_D, nullptr, q,
                                                    TT_M, TT_D, TT_D);
        k_gemm_nt<0, 0, 1><<<gDD, 256, 0, stream>>>(h, Wk_l, bk + l * TT_D, nullptr, kb,
                                                    TT_M, TT_D, TT_D);
        k_gemm_nt<0, 0, 1><<<gDD, 256, 0, stream>>>(h, Wv_l, bv + l * TT_D, nullptr, vb,
                                                    TT_M, TT_D, TT_D);
        k_attn<<<dim3(TT_S / 64, TT_H, TT_B), 256, 0, stream>>>(q, kb, vb, o);
        k_gemm_nt<0, 1, 1><<<gDD, 256, 0, stream>>>(o, Wo_l, bo + l * TT_D, x, x,
                                                    TT_M, TT_D, TT_D);
        k_layernorm<<<TT_M / 4, 256, 0, stream>>>(x, ln2w + l * TT_D, ln2b + l * TT_D, h);
        k_gemm_nt<1, 0, 1><<<gF1, 256, 0, stream>>>(h, W1_l, b1 + l * TT_DFF, nullptr, mid,
                                                    TT_M, TT_DFF, TT_D);
        k_gemm_nt<0, 1, 1><<<gDD, 256, 0, stream>>>(mid, W2_l, b2 + l * TT_D, x, x,
                                                    TT_M, TT_D, TT_DFF);
    }

    k_layernorm<<<TT_M / 4, 256, 0, stream>>>(x, lnfw, lnfb, h);
    k_gemm_nt<0, 0, 0><<<gHd, 256, 0, stream>>>(h, tok, nullptr, nullptr, out,
                                                TT_M, TT_V, TT_D);
}

// Round 2
// 2295.406 us; speedup vs baseline: 2.2347x; 2.2347x over previous
//
#include <hip/hip_runtime.h>
#include <math.h>

// TinyTransformerLM — round 2: f16 MFMA GEMMs, fp32 attention unchanged.
// V=32000 D=512 L=4 H=8 DFF=2048 S=1024 B=4 DK=64.
#define TT_V   32000
#define TT_D   512
#define TT_L   4
#define TT_H   8
#define TT_DFF 2048
#define TT_S   1024
#define TT_B   4
#define TT_DK  64
#define TT_M   (TT_B * TT_S)   /* 4096 token rows */
#define TT_EPS 1e-5f

typedef _Float16 f16;
typedef _Float16 f16x8 __attribute__((ext_vector_type(8)));
typedef _Float16 f16x4 __attribute__((ext_vector_type(4)));
typedef float    f32x4 __attribute__((ext_vector_type(4)));

// ---------------------------------------------------------------- converts
// plain f32 -> f16, 8 elems/thread
__global__ __launch_bounds__(256) void k_cvt(const float* __restrict__ src,
                                             f16* __restrict__ dst) {
    const size_t i = (size_t)blockIdx.x * 256 + threadIdx.x;
    float4 a = ((const float4*)src)[2 * i];
    float4 b = ((const float4*)src)[2 * i + 1];
    f16x8 o;
    o[0] = (f16)a.x; o[1] = (f16)a.y; o[2] = (f16)a.z; o[3] = (f16)a.w;
    o[4] = (f16)b.x; o[5] = (f16)b.y; o[6] = (f16)b.z; o[7] = (f16)b.w;
    *(f16x8*)(dst + 8 * i) = o;
}

// Wq/Wk/Wv [L,D,D] -> interleaved wqkv16 [L][3][D][D], slot t
__global__ __launch_bounds__(256) void k_cvt_qkv(const float* __restrict__ src,
                                                 f16* __restrict__ dst, int t) {
    const size_t i = (size_t)blockIdx.x * 256 + threadIdx.x;
    const size_t e = 8 * i;                       // element idx in [L*D*D)
    const size_t l = e >> 18;                     // D*D = 262144 = 2^18
    const size_t rem = e & ((1u << 18) - 1);
    float4 a = ((const float4*)src)[2 * i];
    float4 b = ((const float4*)src)[2 * i + 1];
    f16x8 o;
    o[0] = (f16)a.x; o[1] = (f16)a.y; o[2] = (f16)a.z; o[3] = (f16)a.w;
    o[4] = (f16)b.x; o[5] = (f16)b.y; o[6] = (f16)b.z; o[7] = (f16)b.w;
    *(f16x8*)(dst + l * 3 * 262144 + (size_t)t * 262144 + rem) = o;
}

// bq/bk/bv [L,512] each -> bqkv [L][1536] fp32
__global__ __launch_bounds__(256) void k_cat_bias(const float* __restrict__ bq,
                                                  const float* __restrict__ bk,
                                                  const float* __restrict__ bv,
                                                  float* __restrict__ dst) {
    const int i = blockIdx.x * 256 + threadIdx.x;   // < L*1536
    const int l = i / 1536, j = i % 1536;
    const int t = j >> 9, jj = j & 511;
    const float* s = (t == 0) ? bq : (t == 1) ? bk : bv;
    dst[i] = s[l * 512 + jj];
}

// ---------------------------------------------------------------- embed
__global__ __launch_bounds__(128) void k_embed(const int* __restrict__ idx,
                                               const float* __restrict__ tok,
                                               const float* __restrict__ pos,
                                               float* __restrict__ x) {
    const int row = blockIdx.x;
    const int s   = row & (TT_S - 1);
    const int t   = idx[row];
    const float4* tp = (const float4*)(tok + (size_t)t * TT_D);
    const float4* pp = (const float4*)(pos + (size_t)s * TT_D);
    float4* xp = (float4*)(x + (size_t)row * TT_D);
    const int i = threadIdx.x;
    float4 a = tp[i], b = pp[i];
    xp[i] = make_float4(a.x + b.x, a.y + b.y, a.z + b.z, a.w + b.w);
}

// ---------------------------------------------------------------- layernorm -> f16
__global__ __launch_bounds__(256) void k_layernorm_f16(const float* __restrict__ in,
                                                       const float* __restrict__ w,
                                                       const float* __restrict__ b,
                                                       f16* __restrict__ out) {
    const int row  = blockIdx.x * 4 + (threadIdx.x >> 6);
    const int lane = threadIdx.x & 63;
    const float4* xr = (const float4*)(in + (size_t)row * TT_D);
    float4 v0 = xr[lane];
    float4 v1 = xr[lane + 64];
    float sum = v0.x + v0.y + v0.z + v0.w + v1.x + v1.y + v1.z + v1.w;
#pragma unroll
    for (int off = 32; off >= 1; off >>= 1) sum += __shfl_xor(sum, off, 64);
    const float mu = sum * (1.0f / TT_D);
    float ss = 0.f, dx;
    dx = v0.x - mu; ss += dx * dx;
    dx = v0.y - mu; ss += dx * dx;
    dx = v0.z - mu; ss += dx * dx;
    dx = v0.w - mu; ss += dx * dx;
    dx = v1.x - mu; ss += dx * dx;
    dx = v1.y - mu; ss += dx * dx;
    dx = v1.z - mu; ss += dx * dx;
    dx = v1.w - mu; ss += dx * dx;
#pragma unroll
    for (int off = 32; off >= 1; off >>= 1) ss += __shfl_xor(ss, off, 64);
    const float rs = rsqrtf(ss * (1.0f / TT_D) + TT_EPS);
    const float4* wp = (const float4*)w;
    const float4* bp = (const float4*)b;
    float4 w0 = wp[lane], w1 = wp[lane + 64];
    float4 b0 = bp[lane], b1 = bp[lane + 64];
    f16x4 o0, o1;
    o0[0] = (f16)((v0.x - mu) * rs * w0.x + b0.x);
    o0[1] = (f16)((v0.y - mu) * rs * w0.y + b0.y);
    o0[2] = (f16)((v0.z - mu) * rs * w0.z + b0.z);
    o0[3] = (f16)((v0.w - mu) * rs * w0.w + b0.w);
    o1[0] = (f16)((v1.x - mu) * rs * w1.x + b1.x);
    o1[1] = (f16)((v1.y - mu) * rs * w1.y + b1.y);
    o1[2] = (f16)((v1.z - mu) * rs * w1.z + b1.z);
    o1[3] = (f16)((v1.w - mu) * rs * w1.w + b1.w);
    *(f16x4*)(out + (size_t)row * TT_D + lane * 4)       = o0;
    *(f16x4*)(out + (size_t)row * TT_D + 256 + lane * 4) = o1;
}

// ---------------------------------------------------------------- f16 MFMA GEMM
// C[M,N] = A[M,K] @ B[N,K]^T (+bias)(+resid fp32)(relu)(out f16 or f32).
// 128x128x32 tile, 4 waves, each wave 64x64 = 4x4 frags of 16x16x32 MFMA.
// LDS rows padded to 40 f16 (80 B) -> frag-read bank stride 20 -> 2-way (free).
// A/B fragments both read 8-contiguous-in-K => contraction correct regardless
// of the hardware 4+4 k-slot split (same sigma on both operands).
template <int BIAS, int RESID, int RELU, int OUTF16>
__global__ __launch_bounds__(256) void k_gemm_f16(const f16* __restrict__ A,
                                                  const f16* __restrict__ B,
                                                  const float* __restrict__ bias,
                                                  const float* __restrict__ resid,
                                                  void* __restrict__ Cout,
                                                  int M, int N, int K) {
    __shared__ f16 As[128][40];
    __shared__ f16 Bs[128][40];
    const int tid  = threadIdx.x;
    const int lane = tid & 63;
    const int wv   = tid >> 6;
    const int wm   = wv >> 1, wn = wv & 1;
    const int r15  = lane & 15, g = lane >> 4;
    const int m0 = blockIdx.y * 128, n0 = blockIdx.x * 128;
    const int sr  = tid >> 1;            // staged row 0..127
    const int sq0 = (tid & 1) * 2;       // two 16B chunks: sq0, sq0+1

    f32x4 acc[4][4];
#pragma unroll
    for (int i = 0; i < 4; ++i)
#pragma unroll
        for (int j = 0; j < 4; ++j) acc[i][j] = (f32x4){0.f, 0.f, 0.f, 0.f};

    for (int k0 = 0; k0 < K; k0 += 32) {
        const uint4 a0 = *(const uint4*)(A + (size_t)(m0 + sr) * K + k0 + sq0 * 8);
        const uint4 a1 = *(const uint4*)(A + (size_t)(m0 + sr) * K + k0 + sq0 * 8 + 8);
        const uint4 b0 = *(const uint4*)(B + (size_t)(n0 + sr) * K + k0 + sq0 * 8);
        const uint4 b1 = *(const uint4*)(B + (size_t)(n0 + sr) * K + k0 + sq0 * 8 + 8);
        __syncthreads();                 // previous iteration's reads done
        *(uint4*)&As[sr][sq0 * 8]     = a0;
        *(uint4*)&As[sr][sq0 * 8 + 8] = a1;
        *(uint4*)&Bs[sr][sq0 * 8]     = b0;
        *(uint4*)&Bs[sr][sq0 * 8 + 8] = b1;
        __syncthreads();
        f16x8 af[4], bf[4];
#pragma unroll
        for (int mi = 0; mi < 4; ++mi)
            af[mi] = *(const f16x8*)&As[wm * 64 + mi * 16 + r15][g * 8];
#pragma unroll
        for (int ni = 0; ni < 4; ++ni)
            bf[ni] = *(const f16x8*)&Bs[wn * 64 + ni * 16 + r15][g * 8];
#pragma unroll
        for (int mi = 0; mi < 4; ++mi)
#pragma unroll
            for (int ni = 0; ni < 4; ++ni)
                acc[mi][ni] = __builtin_amdgcn_mfma_f32_16x16x32_f16(
                    af[mi], bf[ni], acc[mi][ni], 0, 0, 0);
    }

    float bvals[4];
#pragma unroll
    for (int ni = 0; ni < 4; ++ni)
        bvals[ni] = BIAS ? bias[n0 + wn * 64 + ni * 16 + r15] : 0.f;

#pragma unroll
    for (int mi = 0; mi < 4; ++mi)
#pragma unroll
        for (int ni = 0; ni < 4; ++ni)
#pragma unroll
            for (int r = 0; r < 4; ++r) {
                const int m = m0 + wm * 64 + mi * 16 + g * 4 + r;
                const int n = n0 + wn * 64 + ni * 16 + r15;
                float v = acc[mi][ni][r] + bvals[ni];
                if (RESID) v += resid[(size_t)m * N + n];
                if (RELU)  v = fmaxf(v, 0.f);
                if (OUTF16) ((f16*)Cout)[(size_t)m * N + n] = (f16)v;
                else        ((float*)Cout)[(size_t)m * N + n] = v;
            }
}

// ---------------------------------------------------------------- attention
// fp32 flash attention (unchanged structure from round 1). Reads fused qkv
// [M,1536] fp32 (q|k|v), writes o16 [M,512] f16.
__global__ __launch_bounds__(256) void k_attn(const float* __restrict__ qkv,
                                              f16* __restrict__ o16) {
    __shared__ float Qs[64][68];
    __shared__ float Ks[64][68];
    __shared__ float Vs[64][68];
    __shared__ float Ps[64][68];
    const int qt = blockIdx.x;
    const int hh = blockIdx.y;
    const int bb = blockIdx.z;
    const size_t qbase = (size_t)bb * TT_S * 1536 + (size_t)hh * TT_DK;
    const int tid = threadIdx.x;
    const int tr = tid >> 4, tc = tid & 15;

    for (int i = tid; i < 64 * 16; i += 256) {
        const int r = i >> 4, cq = i & 15;
        *(float4*)&Qs[r][cq * 4] =
            *(const float4*)(qkv + qbase + (size_t)(qt * 64 + r) * 1536 + cq * 4);
    }
    float m_run[4], l_run[4], acc[4][4];
#pragma unroll
    for (int i = 0; i < 4; ++i) {
        m_run[i] = -INFINITY;
        l_run[i] = 0.f;
#pragma unroll
        for (int j = 0; j < 4; ++j) acc[i][j] = 0.f;
    }
    __syncthreads();

    for (int kt = 0; kt <= qt; ++kt) {
        for (int i = tid; i < 64 * 16; i += 256) {
            const int r = i >> 4, cq = i & 15;
            *(float4*)&Ks[r][cq * 4] =
                *(const float4*)(qkv + qbase + 512 + (size_t)(kt * 64 + r) * 1536 + cq * 4);
            *(float4*)&Vs[r][cq * 4] =
                *(const float4*)(qkv + qbase + 1024 + (size_t)(kt * 64 + r) * 1536 + cq * 4);
        }
        __syncthreads();

        float s[4][4];
#pragma unroll
        for (int i = 0; i < 4; ++i)
#pragma unroll
            for (int j = 0; j < 4; ++j) s[i][j] = 0.f;
#pragma unroll
        for (int d4 = 0; d4 < 16; ++d4) {
            float4 qv[4], kv[4];
#pragma unroll
            for (int i = 0; i < 4; ++i) qv[i] = *(const float4*)&Qs[tr * 4 + i][d4 * 4];
#pragma unroll
            for (int j = 0; j < 4; ++j) kv[j] = *(const float4*)&Ks[tc * 4 + j][d4 * 4];
#pragma unroll
            for (int i = 0; i < 4; ++i)
#pragma unroll
                for (int j = 0; j < 4; ++j)
                    s[i][j] += qv[i].x * kv[j].x + qv[i].y * kv[j].y +
                               qv[i].z * kv[j].z + qv[i].w * kv[j].w;
        }
#pragma unroll
        for (int i = 0; i < 4; ++i)
#pragma unroll
            for (int j = 0; j < 4; ++j) s[i][j] *= 0.125f;
        if (kt == qt) {
#pragma unroll
            for (int i = 0; i < 4; ++i)
#pragma unroll
                for (int j = 0; j < 4; ++j)
                    if (tc * 4 + j > tr * 4 + i) s[i][j] = -INFINITY;
        }

#pragma unroll
        for (int i = 0; i < 4; ++i) {
            float mx = fmaxf(fmaxf(s[i][0], s[i][1]), fmaxf(s[i][2], s[i][3]));
#pragma unroll
            for (int off = 8; off >= 1; off >>= 1) mx = fmaxf(mx, __shfl_xor(mx, off, 16));
            const float m_new = fmaxf(m_run[i], mx);
            const float sc = expf(m_run[i] - m_new);
            float rsum = 0.f;
#pragma unroll
            for (int j = 0; j < 4; ++j) {
                const float p = expf(s[i][j] - m_new);
                Ps[tr * 4 + i][tc * 4 + j] = p;
                rsum += p;
            }
#pragma unroll
            for (int off = 8; off >= 1; off >>= 1) rsum += __shfl_xor(rsum, off, 16);
            l_run[i] = l_run[i] * sc + rsum;
            m_run[i] = m_new;
#pragma unroll
            for (int j = 0; j < 4; ++j) acc[i][j] *= sc;
        }
        __syncthreads();

        for (int c = 0; c < 64; ++c) {
            const float4 vv = *(const float4*)&Vs[c][tc * 4];
#pragma unroll
            for (int i = 0; i < 4; ++i) {
                const float p = Ps[tr * 4 + i][c];
                acc[i][0] = fmaf(p, vv.x, acc[i][0]);
                acc[i][1] = fmaf(p, vv.y, acc[i][1]);
                acc[i][2] = fmaf(p, vv.z, acc[i][2]);
                acc[i][3] = fmaf(p, vv.w, acc[i][3]);
            }
        }
        __syncthreads();
    }

#pragma unroll
    for (int i = 0; i < 4; ++i) {
        const float inv = 1.f / l_run[i];
        f16x4 o;
        o[0] = (f16)(acc[i][0] * inv);
        o[1] = (f16)(acc[i][1] * inv);
        o[2] = (f16)(acc[i][2] * inv);
        o[3] = (f16)(acc[i][3] * inv);
        *(f16x4*)(o16 + (size_t)(bb * TT_S + qt * 64 + tr * 4 + i) * TT_D +
                  hh * TT_DK + tc * 4) = o;
    }
}

// ---------------------------------------------------------------- launch
extern "C" void kernel_launch(void* const* d_in, const int* in_sizes, int n_in,
                              void* d_out, int out_size, void* d_ws, size_t ws_size,
                              hipStream_t stream) {
    const int*   idx  = (const int*)  d_in[0];
    const float* tok  = (const float*)d_in[1];
    const float* pos  = (const float*)d_in[2];
    const float* Wq   = (const float*)d_in[3];
    const float* bq   = (const float*)d_in[4];
    const float* Wk   = (const float*)d_in[5];
    const float* bk   = (const float*)d_in[6];
    const float* Wv   = (const float*)d_in[7];
    const float* bv   = (const float*)d_in[8];
    const float* Wo   = (const float*)d_in[9];
    const float* bo   = (const float*)d_in[10];
    const float* ln1w = (const float*)d_in[11];
    const float* ln1b = (const float*)d_in[12];
    const float* ln2w = (const float*)d_in[13];
    const float* ln2b = (const float*)d_in[14];
    const float* W1   = (const float*)d_in[15];
    const float* b1   = (const float*)d_in[16];
    const float* W2   = (const float*)d_in[17];
    const float* b2   = (const float*)d_in[18];
    const float* lnfw = (const float*)d_in[19];
    const float* lnfb = (const float*)d_in[20];
    float* out = (float*)d_out;

    // ---- workspace (ws): x fp32, h16, f16 weights, bqkv. ~70 MB total.
    char* w = (char*)d_ws;
    float* x      = (float*)w;                 w += (size_t)TT_M * TT_D * 4;      // 8 MB
    f16*   h16    = (f16*)w;                   w += (size_t)TT_M * TT_D * 2;      // 4 MB
    f16*   wqkv16 = (f16*)w;                   w += (size_t)TT_L * 3 * TT_D * TT_D * 2; // 6.3 MB
    f16*   wo16   = (f16*)w;                   w += (size_t)TT_L * TT_D * TT_D * 2;     // 2.1 MB
    f16*   w116   = (f16*)w;                   w += (size_t)TT_L * TT_DFF * TT_D * 2;   // 8.4 MB
    f16*   w216   = (f16*)w;                   w += (size_t)TT_L * TT_D * TT_DFF * 2;   // 8.4 MB
    f16*   tok16  = (f16*)w;                   w += (size_t)TT_V * TT_D * 2;            // 32.8 MB
    float* bqkv   = (float*)w;                 w += (size_t)TT_L * 1536 * 4;

    // ---- scratch inside d_out (dead before LM head overwrites it)
    char* o2 = (char*)d_out;
    float* qkv  = (float*)o2;                  o2 += (size_t)TT_M * 1536 * 4;     // 25.2 MB
    f16*   o16  = (f16*)o2;                    o2 += (size_t)TT_M * TT_D * 2;     // 4 MB
    f16*   m16  = (f16*)o2;                    // mid: 4096 x 2048 f16, 16.8 MB

    // ---- weight conversions (every launch; ~25 us total)
    k_cvt_qkv<<<512, 256, 0, stream>>>(Wq, wqkv16, 0);
    k_cvt_qkv<<<512, 256, 0, stream>>>(Wk, wqkv16, 1);
    k_cvt_qkv<<<512, 256, 0, stream>>>(Wv, wqkv16, 2);
    k_cvt<<<512,  256, 0, stream>>>(Wo, wo16);
    k_cvt<<<2048, 256, 0, stream>>>(W1, w116);
    k_cvt<<<2048, 256, 0, stream>>>(W2, w216);
    k_cvt<<<8000, 256, 0, stream>>>(tok, tok16);
    k_cat_bias<<<24, 256, 0, stream>>>(bq, bk, bv, bqkv);

    k_embed<<<TT_M, 128, 0, stream>>>(idx, tok, pos, x);

    const dim3 gQKV(1536 / 128, TT_M / 128);   // (12, 32)
    const dim3 gDD(TT_D / 128, TT_M / 128);    // (4, 32)
    const dim3 gF1(TT_DFF / 128, TT_M / 128);  // (16, 32)
    const dim3 gHd(TT_V / 128, TT_M / 128);    // (250, 32)

    for (int l = 0; l < TT_L; ++l) {
        k_layernorm_f16<<<TT_M / 4, 256, 0, stream>>>(x, ln1w + l * TT_D, ln1b + l * TT_D, h16);
        k_gemm_f16<1, 0, 0, 0><<<gQKV, 256, 0, stream>>>(
            h16, wqkv16 + (size_t)l * 3 * TT_D * TT_D, bqkv + l * 1536, nullptr,
            qkv, TT_M, 1536, TT_D);
        k_attn<<<dim3(TT_S / 64, TT_H, TT_B), 256, 0, stream>>>(qkv, o16);
        k_gemm_f16<1, 1, 0, 0><<<gDD, 256, 0, stream>>>(
            o16, wo16 + (size_t)l * TT_D * TT_D, bo + l * TT_D, x,
            x, TT_M, TT_D, TT_D);
        k_layernorm_f16<<<TT_M / 4, 256, 0, stream>>>(x, ln2w + l * TT_D, ln2b + l * TT_D, h16);
        k_gemm_f16<1, 0, 1, 1><<<gF1, 256, 0, stream>>>(
            h16, w116 + (size_t)l * TT_DFF * TT_D, b1 + l * TT_DFF, nullptr,
            m16, TT_M, TT_DFF, TT_D);
        k_gemm_f16<1, 1, 0, 0><<<gDD, 256, 0, stream>>>(
            m16, w216 + (size_t)l * TT_D * TT_DFF, b2 + l * TT_D, x,
            x, TT_M, TT_D, TT_DFF);
    }

    k_layernorm_f16<<<TT_M / 4, 256, 0, stream>>>(x, lnfw, lnfb, h16);
    k_gemm_f16<0, 0, 0, 0><<<gHd, 256, 0, stream>>>(
        h16, tok16, nullptr, nullptr, out, TT_M, TT_V, TT_D);
}